// Round 11
// baseline (90.743 us; speedup 1.0000x reference)
//
#include <hip/hip_runtime.h>
#include <hip/hip_bf16.h>
#include <cstddef>
#include <cstdint>

constexpr int Bb = 16, Ss = 512, Dd = 256, Hh = 8, HDd = 32, Ff = 682;
constexpr int FKp = 704;            // padded K for down GEMM (682 -> 704 = 11*64)
constexpr float EPSf = 1.1920928955078125e-07f;

typedef short bf8v __attribute__((ext_vector_type(8)));
typedef float f4 __attribute__((ext_vector_type(4)));
using bf16 = __hip_bfloat16;

__device__ inline f4 MFMA(bf8v a, bf8v b, f4 c) {
  return __builtin_amdgcn_mfma_f32_16x16x32_bf16(a, b, c, 0, 0, 0);
}

// async global->LDS, 16B per lane; lds dest = wave-uniform base + lane*16
__device__ __forceinline__ void gl_lds16(const bf16* g, bf16* l) {
  __builtin_amdgcn_global_load_lds(
      (const __attribute__((address_space(1))) unsigned int*)(g),
      (__attribute__((address_space(3))) unsigned int*)(l), 16, 0, 0);
}

// ---------------- weight converts + embed+rmsnorm in ONE launch ----------------
__global__ __launch_bounds__(256) void k_prep(
    const float* __restrict__ wq, const float* __restrict__ wk,
    const float* __restrict__ wv, const float* __restrict__ wg,
    const float* __restrict__ wu, const float* __restrict__ wd,
    bf16* __restrict__ dqkv, bf16* __restrict__ dgate,
    bf16* __restrict__ dup, bf16* __restrict__ ddown,
    const float* __restrict__ emb, const float* __restrict__ pos,
    const int* __restrict__ tok, const float* __restrict__ w,
    bf16* __restrict__ hb, bf16* __restrict__ xb)
{
  const int b = blockIdx.x, tid = threadIdx.x;
  if (b < 640) {
    const int idx = b * 256 + tid;
    const int row = idx >> 8, col = idx & 255;
    float v;
    if (row < 256)      v = wq[(size_t)row * 256 + col];
    else if (row < 288) v = wk[(size_t)(row - 256) * 256 + col];
    else if (row < 544) v = wv[(size_t)(row - 288) * 256 + col];
    else                v = 0.f;
    dqkv[idx] = __float2bfloat16(v);
  } else if (b < 2176) {
    const bool isg = b < 1408;
    const int idx = (b - (isg ? 640 : 1408)) * 256 + tid;
    const int row = idx >> 8, col = idx & 255;
    const float* src = isg ? wg : wu;
    float v = (row < Ff) ? src[(size_t)row * 256 + col] : 0.f;
    (isg ? dgate : dup)[idx] = __float2bfloat16(v);
  } else if (b < 2880) {
    const int idx = (b - 2176) * 256 + tid;   // over [256][704]
    const int row = idx / FKp, col = idx - row * FKp;
    float v = (col < Ff) ? wd[(size_t)row * Ff + col] : 0.f;
    ddown[idx] = __float2bfloat16(v);
  } else {
    const int row = b - 2880;
    const int s = row & (Ss - 1);
    const int t = tok[row];
    float v = emb[(size_t)t * Dd + tid] + pos[(size_t)s * Dd + tid];
    float ss = v * v;
    #pragma unroll
    for (int off = 32; off > 0; off >>= 1) ss += __shfl_down(ss, off);
    __shared__ float red[4];
    if ((tid & 63) == 0) red[tid >> 6] = ss;
    __syncthreads();
    const float tot = red[0] + red[1] + red[2] + red[3];
    const float r = rsqrtf(tot * (1.0f / Dd) + EPSf);
    const size_t o = (size_t)row * Dd + tid;
    hb[o] = __float2bfloat16(v);
    xb[o] = __float2bfloat16(v * r * w[tid]);
  }
}

// ---------------- residual add + rmsnorm -> x2_bf ----------------
__global__ __launch_bounds__(256) void k_add_norm(
    const bf16* __restrict__ a, const bf16* __restrict__ hb,
    const float* __restrict__ w, bf16* __restrict__ x2b)
{
  const int row = blockIdx.x;
  const int tid = threadIdx.x;
  const size_t off = (size_t)row * Dd + tid;
  const float v = __bfloat162float(a[off]) + __bfloat162float(hb[off]);
  float ss = v * v;
  #pragma unroll
  for (int o = 32; o > 0; o >>= 1) ss += __shfl_down(ss, o);
  __shared__ float red[4];
  if ((tid & 63) == 0) red[tid >> 6] = ss;
  __syncthreads();
  const float tot = red[0] + red[1] + red[2] + red[3];
  const float r = rsqrtf(tot * (1.0f / Dd) + EPSf);
  x2b[off] = __float2bfloat16(v * r * w[tid]);
}

// ---------------- qkv GEMM: BM=128 BN=64 BK=64, global_load_lds staging ----------------
__global__ __launch_bounds__(256) void k_qkv(
    const bf16* __restrict__ A, const bf16* __restrict__ W,
    const float* __restrict__ bias0, const float* __restrict__ bias1,
    const float* __restrict__ bias2,
    const float* __restrict__ cost, const float* __restrict__ sint,
    bf16* __restrict__ ob0, bf16* __restrict__ ob1, bf16* __restrict__ vt)
{
  __shared__ bf16 As[128 * 64];
  __shared__ bf16 Bs[64 * 64];
  const int tid = threadIdx.x, lane = tid & 63, wv = tid >> 6;
  const int l15 = lane & 15, lg = lane >> 4;
  const int m0 = blockIdx.x * 128, n0 = blockIdx.y * 64;
  const int wr = (wv >> 1) * 64, wc = (wv & 1) * 32;
  const int sr8 = lane >> 3, slot = lane & 7;

  f4 acc[4][2];
  #pragma unroll
  for (int i = 0; i < 4; i++)
    #pragma unroll
    for (int j = 0; j < 2; j++) acc[i][j] = (f4){0.f, 0.f, 0.f, 0.f};

  for (int ks = 0; ks < 4; ks++) {
    const int k0 = ks * 64;
    #pragma unroll
    for (int i = 0; i < 4; i++) {
      const int row = wv * 32 + i * 8 + sr8;
      gl_lds16(&A[(size_t)(m0 + row) * 256 + k0 + slot * 8],
               &As[(wv * 32 + i * 8) * 64]);
    }
    #pragma unroll
    for (int i = 0; i < 2; i++) {
      const int row = wv * 16 + i * 8 + sr8;
      gl_lds16(&W[(size_t)(n0 + row) * 256 + k0 + slot * 8],
               &Bs[(wv * 16 + i * 8) * 64]);
    }
    __syncthreads();
    #pragma unroll
    for (int kk = 0; kk < 64; kk += 32) {
      bf8v af[4], bw[2];
      #pragma unroll
      for (int mi = 0; mi < 4; mi++)
        af[mi] = *(const bf8v*)&As[(wr + mi * 16 + l15) * 64 + kk + lg * 8];
      #pragma unroll
      for (int ni = 0; ni < 2; ni++)
        bw[ni] = *(const bf8v*)&Bs[(wc + ni * 16 + l15) * 64 + kk + lg * 8];
      #pragma unroll
      for (int mi = 0; mi < 4; mi++)
        #pragma unroll
        for (int ni = 0; ni < 2; ni++)
          acc[mi][ni] = MFMA(af[mi], bw[ni], acc[mi][ni]);
    }
    if (ks < 3) __syncthreads();
  }

  #pragma unroll
  for (int mi = 0; mi < 4; mi++) {
    #pragma unroll
    for (int ni = 0; ni < 2; ni++) {
      const int nbase = n0 + wc + ni * 16;
      const int n = nbase + l15;
      if (nbase < 288) {                      // q or k region: rope
        #pragma unroll
        for (int r = 0; r < 4; r++) {
          const int m = m0 + wr + mi * 16 + lg * 4 + r;
          float vb2 = acc[mi][ni][r] + (nbase < 256 ? bias0[n] : bias1[n - 256]);
          int s, hd;
          if (nbase < 256) { const int flat = ((m & 511) << 8) + n; s = (flat >> 5) & 511; hd = n & 31; }
          else             { s = m & 511; hd = n - 256; }
          const float c = cost[s * 32 + hd], sn = sint[s * 32 + hd];
          const float other = __shfl_xor(vb2, 1);
          const float res = (n & 1) ? (other * sn + vb2 * c) : (vb2 * c - other * sn);
          if (nbase < 256) ob0[(size_t)m * 256 + n] = __float2bfloat16(res);
          else             ob1[(size_t)m * 32 + hd] = __float2bfloat16(res);
        }
      } else if (nbase < 544) {               // v region: transpose via C-order reshape
        const int rel = n - 288;              // feature col in vlin, 0..255
        const int hd = rel & 31, rq = rel >> 5;
        const int mb = m0 + wr + mi * 16 + lg * 4;   // base row, mult of 4
        const int b = mb >> 9;
        const float bv = bias2[rel];
        #pragma unroll
        for (int r = 0; r < 4; r++) {
          const int s = (mb + r) & 511;
          // v4[b][h][s4][hd] = vlin[b][s][rel]:  h = s>>6, s4 = (s&63)*8 + rq
          const int hh2 = s >> 6;
          const int s4 = ((s & 63) << 3) + rq;
          vt[((size_t)(b * Hh + hh2) * HDd + hd) * Ss + s4] =
              __float2bfloat16(acc[mi][ni][r] + bv);
        }
      }
    }
  }
}

// ---------------- fused FFN gate+up: BM=128 BN=64 BK=64, global_load_lds ----------------
__global__ __launch_bounds__(256) void k_ffn(
    const bf16* __restrict__ A, const bf16* __restrict__ Wg,
    const bf16* __restrict__ Wu,
    const float* __restrict__ bg, const float* __restrict__ bu,
    bf16* __restrict__ out)
{
  __shared__ bf16 As[128 * 64];
  __shared__ bf16 Gs[64 * 64];
  __shared__ bf16 Us[64 * 64];
  const int tid = threadIdx.x, lane = tid & 63, wv = tid >> 6;
  const int l15 = lane & 15, lg = lane >> 4;
  const int m0 = blockIdx.x * 128, n0 = blockIdx.y * 64;
  const int wr = (wv >> 1) * 64, wc = (wv & 1) * 32;
  const int sr8 = lane >> 3, slot = lane & 7;

  f4 accg[4][2], accu[4][2];
  #pragma unroll
  for (int i = 0; i < 4; i++)
    #pragma unroll
    for (int j = 0; j < 2; j++) {
      accg[i][j] = (f4){0.f, 0.f, 0.f, 0.f};
      accu[i][j] = (f4){0.f, 0.f, 0.f, 0.f};
    }

  for (int ks = 0; ks < 4; ks++) {
    const int k0 = ks * 64;
    #pragma unroll
    for (int i = 0; i < 4; i++) {
      const int row = wv * 32 + i * 8 + sr8;
      gl_lds16(&A[(size_t)(m0 + row) * 256 + k0 + slot * 8],
               &As[(wv * 32 + i * 8) * 64]);
    }
    #pragma unroll
    for (int i = 0; i < 2; i++) {
      const int row = wv * 16 + i * 8 + sr8;
      gl_lds16(&Wg[(size_t)(n0 + row) * 256 + k0 + slot * 8],
               &Gs[(wv * 16 + i * 8) * 64]);
      gl_lds16(&Wu[(size_t)(n0 + row) * 256 + k0 + slot * 8],
               &Us[(wv * 16 + i * 8) * 64]);
    }
    __syncthreads();
    #pragma unroll
    for (int kk = 0; kk < 64; kk += 32) {
      bf8v af[4], bgf[2], buf[2];
      #pragma unroll
      for (int mi = 0; mi < 4; mi++)
        af[mi] = *(const bf8v*)&As[(wr + mi * 16 + l15) * 64 + kk + lg * 8];
      #pragma unroll
      for (int ni = 0; ni < 2; ni++) {
        bgf[ni] = *(const bf8v*)&Gs[(wc + ni * 16 + l15) * 64 + kk + lg * 8];
        buf[ni] = *(const bf8v*)&Us[(wc + ni * 16 + l15) * 64 + kk + lg * 8];
      }
      #pragma unroll
      for (int mi = 0; mi < 4; mi++)
        #pragma unroll
        for (int ni = 0; ni < 2; ni++) {
          accg[mi][ni] = MFMA(af[mi], bgf[ni], accg[mi][ni]);
          accu[mi][ni] = MFMA(af[mi], buf[ni], accu[mi][ni]);
        }
    }
    if (ks < 3) __syncthreads();
  }

  #pragma unroll
  for (int ni = 0; ni < 2; ni++) {
    const int n = n0 + wc + ni * 16 + l15;
    const float bgv = (n < Ff) ? bg[n] : 0.f;
    const float buv = (n < Ff) ? bu[n] : 0.f;
    #pragma unroll
    for (int mi = 0; mi < 4; mi++) {
      #pragma unroll
      for (int r = 0; r < 4; r++) {
        const int m = m0 + wr + mi * 16 + lg * 4 + r;
        float res = 0.f;
        if (n < Ff) {
          const float gv = accg[mi][ni][r] + bgv;
          const float uv = accu[mi][ni][r] + buv;
          res = gv / (1.f + __expf(-gv)) * uv;
        }
        out[(size_t)m * FKp + n] = __float2bfloat16(res);
      }
    }
  }
}

// ---------------- down GEMM: BM=64 BN=64 K=704, global_load_lds ----------------
__global__ __launch_bounds__(256) void k_down(
    const bf16* __restrict__ A, const bf16* __restrict__ W,
    const float* __restrict__ bias, const bf16* __restrict__ resid,
    float* __restrict__ out)
{
  __shared__ bf16 As[64 * 64];
  __shared__ bf16 Bs[64 * 64];
  const int tid = threadIdx.x, lane = tid & 63, wv = tid >> 6;
  const int l15 = lane & 15, lg = lane >> 4;
  const int m0 = blockIdx.x * 64, n0 = blockIdx.y * 64;
  const int wr = (wv >> 1) * 32, wc = (wv & 1) * 32;
  const int sr8 = lane >> 3, slot = lane & 7;

  f4 acc[2][2];
  #pragma unroll
  for (int i = 0; i < 2; i++)
    #pragma unroll
    for (int j = 0; j < 2; j++) acc[i][j] = (f4){0.f, 0.f, 0.f, 0.f};

  for (int ks = 0; ks < 11; ks++) {
    const int k0 = ks * 64;
    #pragma unroll
    for (int i = 0; i < 2; i++) {
      const int rowa = wv * 16 + i * 8 + sr8;
      gl_lds16(&A[(size_t)(m0 + rowa) * FKp + k0 + slot * 8],
               &As[(wv * 16 + i * 8) * 64]);
      gl_lds16(&W[(size_t)(n0 + rowa) * FKp + k0 + slot * 8],
               &Bs[(wv * 16 + i * 8) * 64]);
    }
    __syncthreads();
    #pragma unroll
    for (int kk = 0; kk < 64; kk += 32) {
      bf8v af[2], bw[2];
      #pragma unroll
      for (int mi = 0; mi < 2; mi++)
        af[mi] = *(const bf8v*)&As[(wr + mi * 16 + l15) * 64 + kk + lg * 8];
      #pragma unroll
      for (int ni = 0; ni < 2; ni++)
        bw[ni] = *(const bf8v*)&Bs[(wc + ni * 16 + l15) * 64 + kk + lg * 8];
      #pragma unroll
      for (int mi = 0; mi < 2; mi++)
        #pragma unroll
        for (int ni = 0; ni < 2; ni++)
          acc[mi][ni] = MFMA(af[mi], bw[ni], acc[mi][ni]);
    }
    if (ks < 10) __syncthreads();
  }

  #pragma unroll
  for (int ni = 0; ni < 2; ni++) {
    const int n = n0 + wc + ni * 16 + l15;
    const float bv = bias[n];
    #pragma unroll
    for (int mi = 0; mi < 2; mi++) {
      #pragma unroll
      for (int r = 0; r < 4; r++) {
        const int m = m0 + wr + mi * 16 + lg * 4 + r;
        out[(size_t)m * 256 + n] = acc[mi][ni][r] + bv +
            __bfloat162float(resid[(size_t)m * 256 + n]);
      }
    }
  }
}

// ---------------- MFMA flash attention: swapped QK^T, 1 wave = 1 q-fragment ----
__global__ __launch_bounds__(64) void k_attn_mfma(
    const bf16* __restrict__ q, const bf16* __restrict__ k,
    const bf16* __restrict__ vt, bf16* __restrict__ o)
{
  __shared__ bf16 Ps[16 * 72];         // [q16][72 pad] = 2.3 KB
  const int lane = threadIdx.x;
  const int l15 = lane & 15, lg = lane >> 4;
  const int hh = blockIdx.y, bb = blockIdx.z;
  const int bh = bb * Hh + hh;
  const int qrow = (31 - blockIdx.x) * 16;   // longest blocks dispatch first
  const int lt = (qrow + 15) >> 6;
  const float scale = 0.17677669529663687f;

  const bf16* kg = k + (size_t)bb * Ss * HDd;
  const bf16* vg = vt + (size_t)bh * (Ss * HDd);

  const bf8v qf = *(const bf8v*)&q[((size_t)bh * Ss + qrow + l15) * HDd + lg * 8];

  f4 oacc[2];
  oacc[0] = (f4){0.f, 0.f, 0.f, 0.f};
  oacc[1] = (f4){0.f, 0.f, 0.f, 0.f};
  float m = -3.0e38f, l = 0.f;

  for (int ti = 0; ti <= lt; ti++) {
    const int t0 = ti * 64;

    f4 sf[4];
    __builtin_amdgcn_s_setprio(1);
    #pragma unroll
    for (int tf = 0; tf < 4; tf++) {
      const bf8v kf = *(const bf8v*)&kg[(size_t)(t0 + tf * 16 + l15) * HDd + lg * 8];
      sf[tf] = MFMA(kf, qf, (f4){0.f, 0.f, 0.f, 0.f});
    }
    __builtin_amdgcn_s_setprio(0);

    bf8v vb[2][2];
    #pragma unroll
    for (int kt = 0; kt < 2; kt++)
      #pragma unroll
      for (int hf = 0; hf < 2; hf++)
        vb[kt][hf] = *(const bf8v*)&vg[(size_t)(hf * 16 + l15) * Ss + t0 + kt * 32 + lg * 8];

    float pm = -3.0e38f;
    if (ti == lt) {
      #pragma unroll
      for (int tf = 0; tf < 4; tf++)
        #pragma unroll
        for (int r = 0; r < 4; r++) {
          float sv = sf[tf][r] * scale;
          if (t0 + tf * 16 + lg * 4 + r > qrow + l15) sv = -3.0e38f;
          sf[tf][r] = sv;
          pm = fmaxf(pm, sv);
        }
    } else {
      #pragma unroll
      for (int tf = 0; tf < 4; tf++)
        #pragma unroll
        for (int r = 0; r < 4; r++) {
          const float sv = sf[tf][r] * scale;
          sf[tf][r] = sv;
          pm = fmaxf(pm, sv);
        }
    }
    pm = fmaxf(pm, __shfl_xor(pm, 16));
    pm = fmaxf(pm, __shfl_xor(pm, 32));

    const float nm = fmaxf(m, pm);
    const float corr = __expf(m - nm);
    m = nm;

    float ls = 0.f;
    #pragma unroll
    for (int tf = 0; tf < 4; tf++)
      #pragma unroll
      for (int r = 0; r < 4; r++) {
        const float p = __expf(sf[tf][r] - m);
        sf[tf][r] = p;
        ls += p;
      }
    ls += __shfl_xor(ls, 16);
    ls += __shfl_xor(ls, 32);
    l = l * corr + ls;

    #pragma unroll
    for (int tf = 0; tf < 4; tf++) {
      bf16 t4[4];
      #pragma unroll
      for (int r = 0; r < 4; r++) t4[r] = __float2bfloat16(sf[tf][r]);
      *(uint2*)&Ps[l15 * 72 + tf * 16 + lg * 4] = *(const uint2*)t4;
    }

    float corrT[4];
    #pragma unroll
    for (int r = 0; r < 4; r++) corrT[r] = __shfl(corr, lg * 4 + r);
    #pragma unroll
    for (int hf = 0; hf < 2; hf++)
      #pragma unroll
      for (int r = 0; r < 4; r++) oacc[hf][r] *= corrT[r];

    __builtin_amdgcn_s_setprio(1);
    #pragma unroll
    for (int kt = 0; kt < 2; kt++) {
      const bf8v pv = *(const bf8v*)&Ps[l15 * 72 + kt * 32 + lg * 8];
      #pragma unroll
      for (int hf = 0; hf < 2; hf++)
        oacc[hf] = MFMA(pv, vb[kt][hf], oacc[hf]);
    }
    __builtin_amdgcn_s_setprio(0);
  }

  float lT[4];
  #pragma unroll
  for (int r = 0; r < 4; r++) lT[r] = __shfl(l, lg * 4 + r);
  #pragma unroll
  for (int hf = 0; hf < 2; hf++)
    #pragma unroll
    for (int r = 0; r < 4; r++)
      o[((size_t)bh * Ss + qrow + lg * 4 + r) * HDd + hf * 16 + l15] =
          __float2bfloat16(oacc[hf][r] / lT[r]);
}

extern "C" void kernel_launch(void* const* d_in, const int* in_sizes, int n_in,
                              void* d_out, int out_size, void* d_ws, size_t ws_size,
                              hipStream_t stream)
{
  const float* emb     = (const float*)d_in[0];
  const float* pos_emb = (const float*)d_in[1];
  const float* attn_w  = (const float*)d_in[2];
  const float* wq      = (const float*)d_in[3];
  const float* bq      = (const float*)d_in[4];
  const float* wk      = (const float*)d_in[5];
  const float* bk      = (const float*)d_in[6];
  const float* wv      = (const float*)d_in[7];
  const float* bv      = (const float*)d_in[8];
  const float* cos_t   = (const float*)d_in[9];
  const float* sin_t   = (const float*)d_in[10];
  const float* ffn_w   = (const float*)d_in[11];
  const float* w_gate  = (const float*)d_in[12];
  const float* b_gate  = (const float*)d_in[13];
  const float* w_up    = (const float*)d_in[14];
  const float* b_up    = (const float*)d_in[15];
  const float* w_down  = (const float*)d_in[16];
  const float* b_down  = (const float*)d_in[17];
  const int*   tok     = (const int*)d_in[18];
  float* out = (float*)d_out;

  const size_t NT = (size_t)Bb * Ss;   // 8192
  char* base = (char*)d_ws;
  size_t off = 0;
  auto alloc = [&](size_t bytes) {
    void* r = base + off;
    off = (off + bytes + 255) & ~(size_t)255;
    return r;
  };
  bf16*  h_bf   = (bf16*)alloc(NT * Dd * 2);
  bf16*  x_bf   = (bf16*)alloc(NT * Dd * 2);
  bf16*  q_bf   = (bf16*)alloc(NT * Dd * 2);
  bf16*  k_bf   = (bf16*)alloc(NT * HDd * 2);
  bf16*  vt_bf  = (bf16*)alloc(NT * Dd * 2);
  bf16*  o_bf   = (bf16*)alloc(NT * Dd * 2);
  bf16*  x2_bf  = (bf16*)alloc(NT * Dd * 2);
  bf16*  g_bf   = (bf16*)alloc(NT * (size_t)FKp * 2);
  bf16*  wqkv_b = (bf16*)alloc((size_t)640 * 256 * 2);
  bf16*  wgate_b= (bf16*)alloc((size_t)768 * 256 * 2);
  bf16*  wup_b  = (bf16*)alloc((size_t)768 * 256 * 2);
  bf16*  wdown_b= (bf16*)alloc((size_t)256 * FKp * 2);

  k_prep<<<dim3(2880 + NT), 256, 0, stream>>>(
      wq, wk, wv, w_gate, w_up, w_down, wqkv_b, wgate_b, wup_b, wdown_b,
      emb, pos_emb, tok, attn_w, h_bf, x_bf);

  k_qkv<<<dim3(NT / 128, 10), 256, 0, stream>>>(
      x_bf, wqkv_b, bq, bk, bv, cos_t, sin_t, q_bf, k_bf, vt_bf);

  k_attn_mfma<<<dim3(32, Hh, Bb), 64, 0, stream>>>(q_bf, k_bf, vt_bf, o_bf);

  k_add_norm<<<dim3(NT), 256, 0, stream>>>(o_bf, h_bf, ffn_w, x2_bf);

  k_ffn<<<dim3(NT / 128, 11), 256, 0, stream>>>(
      x2_bf, wgate_b, wup_b, b_gate, b_up, g_bf);

  k_down<<<dim3(NT / 64, 4), 256, 0, stream>>>(
      g_bf, wdown_b, b_down, x2_bf, out);
}